// Round 6
// baseline (6612.983 us; speedup 1.0000x reference)
//
#include <hip/hip_runtime.h>
#include <cstdint>
#include <cstddef>

typedef __bf16 bf16;
typedef float f32x4 __attribute__((ext_vector_type(4)));
typedef bf16 bf16x8 __attribute__((ext_vector_type(8)));
typedef bf16 bf16x4 __attribute__((ext_vector_type(4)));

#define AS1 __attribute__((address_space(1)))
#define AS3 __attribute__((address_space(3)))

__device__ __forceinline__ void gload_lds16(const void* g, void* l) {
  __builtin_amdgcn_global_load_lds((AS1 void*)g, (AS3 void*)l, 16, 0, 0);
}

#define NBLK_W 192  // 64 L0 + 128 L1 worker blocks
// packed epoch flags: flag0[64] | flag1[128] | pad  (1 store/block/step,
// consumers scan with one wave; 12 hot cachelines total -> MALL-resident)
#define FLAG_WORDS 256

// ---------------- init: combined biases + flags ----------------
__global__ __launch_bounds__(256) void init_misc(
    const float* __restrict__ bih0, const float* __restrict__ bhh0,
    const float* __restrict__ bih1, const float* __restrict__ bhh1,
    float* __restrict__ bsum0, float* __restrict__ bsum1, unsigned* __restrict__ flags) {
  int i = blockIdx.x * 256 + threadIdx.x;
  if (i < 4096) {
    bsum0[i] = bih0[i] + bhh0[i];
    bsum1[i] = bih1[i] + bhh1[i];
  }
  if (i < FLAG_WORDS) flags[i] = 0u;
}

// ---------------- embedding gather -> bf16, row = t*16 + b ----------------
__global__ __launch_bounds__(256) void embed_gather(
    const int* __restrict__ x, const float* __restrict__ emb, bf16* __restrict__ xe, int T) {
  int row = blockIdx.x;  // t*16 + b
  int t = row >> 4, b = row & 15;
  int tok = x[b * T + t];
  int cix = threadIdx.x << 2;
  f32x4 v = *(const f32x4*)(emb + ((size_t)tok << 10) + cix);
  bf16x4 o;
  for (int j = 0; j < 4; ++j) o[j] = (bf16)v[j];
  *(bf16x4*)(xe + ((size_t)row << 10) + cix) = o;
}

// ---------------- GEMM: C[M,N] = A[M,K](bf16) * W[N,K](f32->bf16)^T + bias ----------------
template <int OUTMODE>
__global__ __launch_bounds__(256) void gemm_bf16(
    const bf16* __restrict__ A, const float* __restrict__ Bw,
    const float* __restrict__ bias, float* __restrict__ C,
    int M, int N, int K, int Tdim) {
  __shared__ bf16 aL[2][128 * 32];
  __shared__ bf16 bL[2][128 * 32];
  const int tid = threadIdx.x;
  const int l = tid & 63, w = tid >> 6;
  const int nbm = M >> 7;
  const int bm = blockIdx.x % nbm;
  const int bn = blockIdx.x / nbm;
  const int wr = (w >> 1) << 6, wc = (w & 1) << 6;
  const int NT = K >> 5;
  const int r16 = l & 15, kq = l >> 4;

  f32x4 acc[4][4];
  for (int m = 0; m < 4; ++m)
    for (int n = 0; n < 4; ++n) acc[m][n] = (f32x4){0.f, 0.f, 0.f, 0.f};

  for (int i = 0; i < 2; ++i) {
    int lin = tid + (i << 8);
    int r = lin >> 2, s = lin & 3, c = s ^ (r & 3);
    gload_lds16(A + (size_t)((bm << 7) + r) * K + (c << 3), &aL[0][lin << 3]);
  }
  for (int i = 0; i < 2; ++i) {
    int lin = tid + (i << 8);
    int r = lin >> 2, c = lin & 3;
    const float* src = Bw + (size_t)((bn << 7) + r) * K + (c << 3);
    f32x4 v0 = *(const f32x4*)src;
    f32x4 v1 = *(const f32x4*)(src + 4);
    bf16x8 o;
    for (int j = 0; j < 4; ++j) { o[j] = (bf16)v0[j]; o[j + 4] = (bf16)v1[j]; }
    *(bf16x8*)&bL[0][(r << 5) + ((c ^ (r & 3)) << 3)] = o;
  }
  __syncthreads();

  for (int kt = 0; kt < NT; ++kt) {
    const int cur = kt & 1;
    const bool pf = (kt + 1 < NT);
    f32x4 bv0[2], bv1[2];
    int br_[2], bs_[2];
    if (pf) {
      for (int i = 0; i < 2; ++i) {
        int lin = tid + (i << 8);
        int r = lin >> 2, s = lin & 3, c = s ^ (r & 3);
        gload_lds16(A + (size_t)((bm << 7) + r) * K + ((kt + 1) << 5) + (c << 3),
                    &aL[cur ^ 1][lin << 3]);
      }
      for (int i = 0; i < 2; ++i) {
        int lin = tid + (i << 8);
        int r = lin >> 2, c = lin & 3;
        const float* src = Bw + (size_t)((bn << 7) + r) * K + ((kt + 1) << 5) + (c << 3);
        bv0[i] = *(const f32x4*)src;
        bv1[i] = *(const f32x4*)(src + 4);
        br_[i] = r;
        bs_[i] = c ^ (r & 3);
      }
    }
    bf16x8 af[4], bfr[4];
    for (int m = 0; m < 4; ++m) {
      int row = wr + (m << 4) + r16;
      int ch = kq ^ (row & 3);
      af[m] = *(const bf16x8*)&aL[cur][(row << 5) + (ch << 3)];
    }
    for (int n = 0; n < 4; ++n) {
      int row = wc + (n << 4) + r16;
      int ch = kq ^ (row & 3);
      bfr[n] = *(const bf16x8*)&bL[cur][(row << 5) + (ch << 3)];
    }
    for (int m = 0; m < 4; ++m)
      for (int n = 0; n < 4; ++n)
        acc[m][n] = __builtin_amdgcn_mfma_f32_16x16x32_bf16(af[m], bfr[n], acc[m][n], 0, 0, 0);
    if (pf) {
      for (int i = 0; i < 2; ++i) {
        bf16x8 o;
        for (int j = 0; j < 4; ++j) { o[j] = (bf16)bv0[i][j]; o[j + 4] = (bf16)bv1[i][j]; }
        *(bf16x8*)&bL[cur ^ 1][(br_[i] << 5) + (bs_[i] << 3)] = o;
      }
    }
    __syncthreads();
  }

  float bvv[4];
  for (int n = 0; n < 4; ++n) bvv[n] = bias[(bn << 7) + wc + (n << 4) + r16];
  for (int m = 0; m < 4; ++m) {
    int Rbase = (bm << 7) + wr + (m << 4) + (kq << 2);
    for (int r = 0; r < 4; ++r) {
      int R = Rbase + r;
      size_t rowoff;
      if (OUTMODE == 0) {
        rowoff = (size_t)R * N;
      } else {
        int tt = R >> 4, bb = R & 15;
        rowoff = ((size_t)bb * Tdim + tt) * N;
      }
      for (int n = 0; n < 4; ++n)
        C[rowoff + (bn << 7) + wc + (n << 4) + r16] = acc[m][n][r] + bvv[n];
    }
  }
}

// ---------------- scan-signal pipelined 2-layer persistent LSTM ----------------
// bid 0..63 = layer 0 (16 cols), bid 64..191 = layer 1 (8 cols).
// Producer signaling: ONE dword per block per step into a packed epoch array
// (flag0[64] / flag1[128] = 12 cachelines total, MALL-resident).
// Consumer wait: one wave scans the packed words (lane l polls word l);
// the divergent-exit spin is the AND over all producers.
__global__ __launch_bounds__(256, 1) void lstm_pipe(
    const float* __restrict__ gx,     // [T*16][4096] = xe@Wih0^T + bsum0
    const float* __restrict__ Whh0,   // [4096][1024] f32
    const float* __restrict__ Wih1,   // [4096][1024] f32
    const float* __restrict__ Whh1,   // [4096][1024] f32
    const float* __restrict__ bsum1,  // [4096]
    bf16* __restrict__ hs0,           // [T*16][1024]
    bf16* __restrict__ hs1,           // [T*16][1024]
    unsigned* __restrict__ flags,     // FLAG_WORDS, zeroed
    int T) {
  __shared__ bf16 wlds[64 * 1024];     // 128 KiB, swizzled (chunk ^= row&7)
  __shared__ float glds[4 * 16 * 16];  // gate exchange
  const int tid = threadIdx.x;
  const int l = tid & 63, w = tid >> 6;
  const int bid = blockIdx.x;
  unsigned* const flag0 = flags;        // [64]  epoch of L0 block p
  unsigned* const flag1 = flags + 64;   // [128] epoch of L1 block q

  const bool L0 = bid < 64;
  const int r16 = l & 15, kq = l >> 4, rx = r16 & 7;

  // ---- stage weight slices to LDS (f32 -> bf16, swizzled) ----
  if (L0) {
    const int j0s = bid << 4;
    for (int it = 0; it < 32; ++it) {
      int lin = tid + (it << 8);
      int row = lin >> 7, cs = lin & 127, c = cs ^ (row & 7);
      int g = row >> 4, n = row & 15;
      const float* src = Whh0 + (size_t)(g * 1024 + j0s + n) * 1024 + (c << 3);
      f32x4 v0 = *(const f32x4*)src;
      f32x4 v1 = *(const f32x4*)(src + 4);
      bf16x8 o;
      for (int j = 0; j < 4; ++j) { o[j] = (bf16)v0[j]; o[j + 4] = (bf16)v1[j]; }
      *(bf16x8*)(wlds + (row << 10) + (cs << 3)) = o;
    }
  } else {
    const int j0s = (bid - 64) << 3;
    for (int it = 0; it < 32; ++it) {
      int lin = tid + (it << 8);
      int row = lin >> 7, cs = lin & 127, c = cs ^ (row & 7);
      int m = row >> 5, rr = row & 31, g = rr >> 3, n = rr & 7;
      const float* W = m ? Whh1 : Wih1;
      const float* src = W + (size_t)(g * 1024 + j0s + n) * 1024 + (c << 3);
      f32x4 v0 = *(const f32x4*)src;
      f32x4 v1 = *(const f32x4*)(src + 4);
      bf16x8 o;
      for (int j = 0; j < 4; ++j) { o[j] = (bf16)v0[j]; o[j + 4] = (bf16)v1[j]; }
      *(bf16x8*)(wlds + (row << 10) + (cs << 3)) = o;
    }
  }
  __syncthreads();

  if (L0) {
    const int j0 = bid << 4;
    const int bidx = tid >> 4, jl = tid & 15;
    float cst = 0.f;

    for (int t = 0; t < T; ++t) {
      // prefetch gx for this step (overlaps the flag wait)
      const float* gp = gx + ((((size_t)t << 4) + bidx) << 12) + j0 + jl;
      float gi = gp[0], gf = gp[1024], gg2 = gp[2048], go_ = gp[3072];
      // wait: all 64 L0 producers at epoch >= t (h0[t-1] complete); lane l
      // polls producer l's packed word; divergent exit = AND over producers
      if (t > 0 && w == 0) {
        const unsigned* fp = flag0 + l;
        while (__hip_atomic_load(fp, __ATOMIC_RELAXED, __HIP_MEMORY_SCOPE_AGENT) <
               (unsigned)t) {
        }
      }
      __syncthreads();
      asm volatile("" ::: "memory");

      f32x4 acc = (f32x4){0.f, 0.f, 0.f, 0.f};
      f32x4 acc2 = (f32x4){0.f, 0.f, 0.f, 0.f};
      if (t > 0) {
        const bf16* hp = hs0 + ((size_t)(t - 1) << 14) + (r16 << 10) + (kq << 3);
        const bf16* wb = wlds + (((w << 4) + r16) << 10);
#pragma unroll 8
        for (int kk = 0; kk < 32; kk += 2) {
          bf16x8 a0 = *(const bf16x8*)(hp + (kk << 5));
          bf16x8 a1 = *(const bf16x8*)(hp + ((kk + 1) << 5));
          acc = __builtin_amdgcn_mfma_f32_16x16x32_bf16(
              a0, *(const bf16x8*)(wb + ((((kk << 2) + kq) ^ rx) << 3)), acc, 0, 0, 0);
          acc2 = __builtin_amdgcn_mfma_f32_16x16x32_bf16(
              a1, *(const bf16x8*)(wb + (((((kk + 1) << 2) + kq) ^ rx) << 3)), acc2, 0, 0, 0);
        }
      }
      for (int r = 0; r < 4; ++r)
        glds[(w << 8) + (((kq << 2) + r) << 4) + r16] = acc[r] + acc2[r];
      __syncthreads();

      float xi = glds[(bidx << 4) + jl] + gi;
      float xf = glds[256 + (bidx << 4) + jl] + gf;
      float xg = glds[512 + (bidx << 4) + jl] + gg2;
      float xo = glds[768 + (bidx << 4) + jl] + go_;
      float ig = 1.f / (1.f + __expf(-xi));
      float fg = 1.f / (1.f + __expf(-xf));
      float eg = __expf(2.f * xg);
      float ggv = 1.f - 2.f / (eg + 1.f);
      float og = 1.f / (1.f + __expf(-xo));
      cst = fg * cst + ig * ggv;
      float ec = __expf(2.f * cst);
      float th = 1.f - 2.f / (ec + 1.f);
      bf16 hb = (bf16)(og * th);
      unsigned hu = (unsigned)__builtin_bit_cast(unsigned short, hb);
      unsigned other = (unsigned)__shfl_xor((int)hu, 1, 64);
      if (!(tid & 1)) {
        unsigned pair = (hu & 0xffffu) | (other << 16);
        bf16* sp = hs0 + ((((size_t)t << 4) + bidx) << 10) + j0 + jl;
        asm volatile("global_store_dword %0, %1, off sc1" ::"v"(sp), "v"(pair) : "memory");
      }
      asm volatile("s_waitcnt vmcnt(0)" ::: "memory");
      __syncthreads();  // all waves' write-through stores MALL-acked

      // signal: ONE dword per block per step
      if (tid == 0)
        __hip_atomic_store(flag0 + bid, (unsigned)(t + 1), __ATOMIC_RELAXED,
                           __HIP_MEMORY_SCOPE_AGENT);
    }
  } else {
    const int q = bid - 64;  // 0..127
    const int j0 = q << 3;
    const int b1 = tid >> 3, j1 = tid & 7;
    float cst = 0.f;
    float bi_ = 0.f, bf_ = 0.f, bg_ = 0.f, bo_ = 0.f;
    if (tid < 128) {
      bi_ = bsum1[j0 + j1];
      bf_ = bsum1[1024 + j0 + j1];
      bg_ = bsum1[2048 + j0 + j1];
      bo_ = bsum1[3072 + j0 + j1];
    }

    for (int t1 = 0; t1 < T; ++t1) {
      // wait: h0[t1] ready (all flag0 >= t1+1); h1[t1-1] ready (all flag1 >= t1)
      if (w == 0) {
        const unsigned* fp = flag0 + l;
        while (__hip_atomic_load(fp, __ATOMIC_RELAXED, __HIP_MEMORY_SCOPE_AGENT) <
               (unsigned)(t1 + 1)) {
        }
      } else if (w == 1 && t1 > 0) {
        const unsigned* fp = flag1 + l;
        while (__hip_atomic_load(fp, __ATOMIC_RELAXED, __HIP_MEMORY_SCOPE_AGENT) <
               (unsigned)t1) {
        }
      } else if (w == 2 && t1 > 0) {
        const unsigned* fp = flag1 + 64 + l;
        while (__hip_atomic_load(fp, __ATOMIC_RELAXED, __HIP_MEMORY_SCOPE_AGENT) <
               (unsigned)t1) {
        }
      }
      __syncthreads();
      asm volatile("" ::: "memory");

      f32x4 acc0 = (f32x4){0.f, 0.f, 0.f, 0.f};
      f32x4 acc1 = (f32x4){0.f, 0.f, 0.f, 0.f};
      const bf16* hp0 = hs0 + ((size_t)t1 << 14) + (r16 << 10) + (kq << 3);
      const bf16* wb0 = wlds + (((w << 3) + rx) << 10);       // Wih1 rows
      const bf16* wb1 = wlds + ((32 + (w << 3) + rx) << 10);  // Whh1 rows
#pragma unroll 8
      for (int kk = 0; kk < 32; ++kk) {
        bf16x8 a0 = *(const bf16x8*)(hp0 + (kk << 5));
        acc0 = __builtin_amdgcn_mfma_f32_16x16x32_bf16(
            a0, *(const bf16x8*)(wb0 + ((((kk << 2) + kq) ^ rx) << 3)), acc0, 0, 0, 0);
      }
      if (t1 > 0) {
        const bf16* hp1 = hs1 + ((size_t)(t1 - 1) << 14) + (r16 << 10) + (kq << 3);
#pragma unroll 8
        for (int kk = 0; kk < 32; ++kk) {
          bf16x8 a1 = *(const bf16x8*)(hp1 + (kk << 5));
          acc1 = __builtin_amdgcn_mfma_f32_16x16x32_bf16(
              a1, *(const bf16x8*)(wb1 + ((((kk << 2) + kq) ^ rx) << 3)), acc1, 0, 0, 0);
        }
      }
      for (int r = 0; r < 4; ++r)
        glds[(w << 8) + (((kq << 2) + r) << 4) + r16] = acc0[r] + acc1[r];
      __syncthreads();

      if (tid < 128) {
        float xi = glds[(b1 << 4) + j1] + bi_;
        float xf = glds[256 + (b1 << 4) + j1] + bf_;
        float xg = glds[512 + (b1 << 4) + j1] + bg_;
        float xo = glds[768 + (b1 << 4) + j1] + bo_;
        float ig = 1.f / (1.f + __expf(-xi));
        float fg = 1.f / (1.f + __expf(-xf));
        float eg = __expf(2.f * xg);
        float ggv = 1.f - 2.f / (eg + 1.f);
        float og = 1.f / (1.f + __expf(-xo));
        cst = fg * cst + ig * ggv;
        float ec = __expf(2.f * cst);
        float th = 1.f - 2.f / (ec + 1.f);
        bf16 hb = (bf16)(og * th);
        unsigned hu = (unsigned)__builtin_bit_cast(unsigned short, hb);
        unsigned other = (unsigned)__shfl_xor((int)hu, 1, 64);
        if (!(tid & 1)) {
          unsigned pair = (hu & 0xffffu) | (other << 16);
          bf16* sp = hs1 + ((((size_t)t1 << 4) + b1) << 10) + j0 + j1;
          asm volatile("global_store_dword %0, %1, off sc1" ::"v"(sp), "v"(pair) : "memory");
        }
      }
      asm volatile("s_waitcnt vmcnt(0)" ::: "memory");
      __syncthreads();

      if (tid == 0)
        __hip_atomic_store(flag1 + q, (unsigned)(t1 + 1), __ATOMIC_RELAXED,
                           __HIP_MEMORY_SCOPE_AGENT);
    }
  }
}

extern "C" void kernel_launch(void* const* d_in, const int* in_sizes, int n_in,
                              void* d_out, int out_size, void* d_ws, size_t ws_size,
                              hipStream_t stream) {
  const int* x = (const int*)d_in[0];
  const float* emb = (const float*)d_in[1];
  const float* Wih0 = (const float*)d_in[2];
  const float* Whh0 = (const float*)d_in[3];
  const float* bih0 = (const float*)d_in[4];
  const float* bhh0 = (const float*)d_in[5];
  const float* Wih1 = (const float*)d_in[6];
  const float* Whh1 = (const float*)d_in[7];
  const float* bih1 = (const float*)d_in[8];
  const float* bhh1 = (const float*)d_in[9];
  const float* Wout = (const float*)d_in[10];
  const float* bout = (const float*)d_in[11];

  const int T = 512, H = 1024, V = 32000;
  const int M = T * 16;
  const size_t bfb = (size_t)M * H * 2;  // 16 MiB bf16 plane

  char* p = (char*)d_ws;
  bf16* hs1 = (bf16*)p;           p += bfb;  // must survive into projection -> ws
  float* bsum0 = (float*)p;       p += 4096 * 4;
  float* bsum1 = (float*)p;       p += 4096 * 4;
  unsigned* flags = (unsigned*)p; p += FLAG_WORDS * 4;
  size_t base_need = (size_t)(p - (char*)d_ws);
  bf16 *xe, *hs0;
  if (ws_size >= base_need + 2 * bfb) {
    xe = (bf16*)p;
    hs0 = (bf16*)(p + bfb);
  } else {  // d_out tail is dead until projection overwrites it
    char* tail = (char*)d_out + (size_t)out_size * 4 - 2 * bfb;
    xe = (bf16*)tail;
    hs0 = (bf16*)(tail + bfb);
  }
  float* gx = (float*)d_out;  // 134 MB scratch at head of d_out

  init_misc<<<64, 256, 0, stream>>>(bih0, bhh0, bih1, bhh1, bsum0, bsum1, flags);
  embed_gather<<<M, 256, 0, stream>>>(x, emb, xe, T);
  gemm_bf16<0><<<(M / 128) * (4096 / 128), 256, 0, stream>>>(xe, Wih0, bsum0, gx, M, 4096, H, 0);
  lstm_pipe<<<NBLK_W, 256, 0, stream>>>(gx, Whh0, Wih1, Whh1, bsum1, hs0, hs1, flags, T);
  gemm_bf16<1><<<(M / 128) * (V / 128), 256, 0, stream>>>(hs1, Wout, bout, (float*)d_out, M, V, H, T);
}

// Round 7
// 5293.802 us; speedup vs baseline: 1.2492x; 1.2492x over previous
//
#include <hip/hip_runtime.h>
#include <cstdint>
#include <cstddef>

typedef __bf16 bf16;
typedef float f32x4 __attribute__((ext_vector_type(4)));
typedef bf16 bf16x8 __attribute__((ext_vector_type(8)));
typedef bf16 bf16x4 __attribute__((ext_vector_type(4)));

#define AS1 __attribute__((address_space(1)))
#define AS3 __attribute__((address_space(3)))

__device__ __forceinline__ void gload_lds16(const void* g, void* l) {
  __builtin_amdgcn_global_load_lds((AS1 void*)g, (AS3 void*)l, 16, 0, 0);
}

#define RING 8
// flags: fL0[256] | fB[256] | fL1[256] | pad
#define FLAG_WORDS 1024

// ---------------- init: combined biases + flags ----------------
__global__ __launch_bounds__(256) void init_misc(
    const float* __restrict__ bih0, const float* __restrict__ bhh0,
    const float* __restrict__ bih1, const float* __restrict__ bhh1,
    float* __restrict__ bsum0, float* __restrict__ bsum1, unsigned* __restrict__ flags) {
  int i = blockIdx.x * 256 + threadIdx.x;
  if (i < 4096) {
    bsum0[i] = bih0[i] + bhh0[i];
    bsum1[i] = bih1[i] + bhh1[i];
  }
  if (i < FLAG_WORDS) flags[i] = 0u;
}

// ---------------- embedding gather -> bf16, row = t*16 + b ----------------
__global__ __launch_bounds__(256) void embed_gather(
    const int* __restrict__ x, const float* __restrict__ emb, bf16* __restrict__ xe, int T) {
  int row = blockIdx.x;  // t*16 + b
  int t = row >> 4, b = row & 15;
  int tok = x[b * T + t];
  int cix = threadIdx.x << 2;
  f32x4 v = *(const f32x4*)(emb + ((size_t)tok << 10) + cix);
  bf16x4 o;
  for (int j = 0; j < 4; ++j) o[j] = (bf16)v[j];
  *(bf16x4*)(xe + ((size_t)row << 10) + cix) = o;
}

// ---------------- GEMM: C[M,N] = A[M,K](bf16) * W[N,K](f32->bf16)^T + bias ----------------
template <int OUTMODE>
__global__ __launch_bounds__(256) void gemm_bf16(
    const bf16* __restrict__ A, const float* __restrict__ Bw,
    const float* __restrict__ bias, float* __restrict__ C,
    int M, int N, int K, int Tdim) {
  __shared__ bf16 aL[2][128 * 32];
  __shared__ bf16 bL[2][128 * 32];
  const int tid = threadIdx.x;
  const int l = tid & 63, w = tid >> 6;
  const int nbm = M >> 7;
  const int bm = blockIdx.x % nbm;
  const int bn = blockIdx.x / nbm;
  const int wr = (w >> 1) << 6, wc = (w & 1) << 6;
  const int NT = K >> 5;
  const int r16 = l & 15, kq = l >> 4;

  f32x4 acc[4][4];
  for (int m = 0; m < 4; ++m)
    for (int n = 0; n < 4; ++n) acc[m][n] = (f32x4){0.f, 0.f, 0.f, 0.f};

  for (int i = 0; i < 2; ++i) {
    int lin = tid + (i << 8);
    int r = lin >> 2, s = lin & 3, c = s ^ (r & 3);
    gload_lds16(A + (size_t)((bm << 7) + r) * K + (c << 3), &aL[0][lin << 3]);
  }
  for (int i = 0; i < 2; ++i) {
    int lin = tid + (i << 8);
    int r = lin >> 2, c = lin & 3;
    const float* src = Bw + (size_t)((bn << 7) + r) * K + (c << 3);
    f32x4 v0 = *(const f32x4*)src;
    f32x4 v1 = *(const f32x4*)(src + 4);
    bf16x8 o;
    for (int j = 0; j < 4; ++j) { o[j] = (bf16)v0[j]; o[j + 4] = (bf16)v1[j]; }
    *(bf16x8*)&bL[0][(r << 5) + ((c ^ (r & 3)) << 3)] = o;
  }
  __syncthreads();

  for (int kt = 0; kt < NT; ++kt) {
    const int cur = kt & 1;
    const bool pf = (kt + 1 < NT);
    f32x4 bv0[2], bv1[2];
    int br_[2], bs_[2];
    if (pf) {
      for (int i = 0; i < 2; ++i) {
        int lin = tid + (i << 8);
        int r = lin >> 2, s = lin & 3, c = s ^ (r & 3);
        gload_lds16(A + (size_t)((bm << 7) + r) * K + ((kt + 1) << 5) + (c << 3),
                    &aL[cur ^ 1][lin << 3]);
      }
      for (int i = 0; i < 2; ++i) {
        int lin = tid + (i << 8);
        int r = lin >> 2, c = lin & 3;
        const float* src = Bw + (size_t)((bn << 7) + r) * K + ((kt + 1) << 5) + (c << 3);
        bv0[i] = *(const f32x4*)src;
        bv1[i] = *(const f32x4*)(src + 4);
        br_[i] = r;
        bs_[i] = c ^ (r & 3);
      }
    }
    bf16x8 af[4], bfr[4];
    for (int m = 0; m < 4; ++m) {
      int row = wr + (m << 4) + r16;
      int ch = kq ^ (row & 3);
      af[m] = *(const bf16x8*)&aL[cur][(row << 5) + (ch << 3)];
    }
    for (int n = 0; n < 4; ++n) {
      int row = wc + (n << 4) + r16;
      int ch = kq ^ (row & 3);
      bfr[n] = *(const bf16x8*)&bL[cur][(row << 5) + (ch << 3)];
    }
    for (int m = 0; m < 4; ++m)
      for (int n = 0; n < 4; ++n)
        acc[m][n] = __builtin_amdgcn_mfma_f32_16x16x32_bf16(af[m], bfr[n], acc[m][n], 0, 0, 0);
    if (pf) {
      for (int i = 0; i < 2; ++i) {
        bf16x8 o;
        for (int j = 0; j < 4; ++j) { o[j] = (bf16)bv0[i][j]; o[j + 4] = (bf16)bv1[i][j]; }
        *(bf16x8*)&bL[cur ^ 1][(br_[i] << 5) + (bs_[i] << 3)] = o;
      }
    }
    __syncthreads();
  }

  float bvv[4];
  for (int n = 0; n < 4; ++n) bvv[n] = bias[(bn << 7) + wc + (n << 4) + r16];
  for (int m = 0; m < 4; ++m) {
    int Rbase = (bm << 7) + wr + (m << 4) + (kq << 2);
    for (int r = 0; r < 4; ++r) {
      int R = Rbase + r;
      size_t rowoff;
      if (OUTMODE == 0) {
        rowoff = (size_t)R * N;
      } else {
        int tt = R >> 4, bb = R & 15;
        rowoff = ((size_t)bb * Tdim + tt) * N;
      }
      for (int n = 0; n < 4; ++n)
        C[rowoff + (bn << 7) + wc + (n << 4) + r16] = acc[m][n][r] + bvv[n];
    }
  }
}

// ---------------- wave-granular 3-group persistent LSTM pipeline ----------------
// Blocks 0..63  (L0): h0 recurrence, wave = 4 cols x 4 gates of Whh0 (32KB LDS).
// Blocks 64..127 (B): gx1[t] = Wih1*h0[t] + bsum1 into 8-slot ring (1-step slack).
// Blocks 128..191(L1): h1 recurrence with Whh1 + ring gx1.
// No block barriers in the loop: per-wave MFMA chain (N=16 = 4gates x 4cols),
// gate fusion via 3 shfl_xor rounds, 128B full-line tile stores, per-wave flags.
// h tile format: step plane = 256 tiles x [16 b][4 cols] bf16 (128B each).
__global__ __launch_bounds__(256, 1) void lstm_pipe3(
    const float* __restrict__ gx,     // [T*16][4096] = xe@Wih0^T + bsum0
    const float* __restrict__ Whh0,   // [4096][1024] f32
    const float* __restrict__ Wih1,   // [4096][1024] f32
    const float* __restrict__ Whh1,   // [4096][1024] f32
    const float* __restrict__ bsum1,  // [4096]
    bf16* __restrict__ hs0t,          // [T][16384] tile format
    bf16* __restrict__ hs1t,          // [T][16384] tile format
    float* __restrict__ gx1,          // ring [8][65536] f32
    bf16* __restrict__ hs1rm,         // [T*16][1024] row-major (projection input)
    unsigned* __restrict__ flags,     // FLAG_WORDS, zeroed
    int T) {
  __shared__ bf16 wlds[4][16 * 1024];     // 32KB per wave
  __shared__ unsigned short hb[4][64];    // per-wave transpose bounce (128B)
  __shared__ unsigned tokv[4];
  const int tid = threadIdx.x;
  const int l = tid & 63, w = tid >> 6;
  const int bid = blockIdx.x;
  const int r16 = l & 15, kq = l >> 4;
  unsigned* const fL0 = flags;
  unsigned* const fB = flags + 256;
  unsigned* const fL1 = flags + 512;
  const int typ = bid >> 6;  // 0=L0, 1=B, 2=L1
  const int lb = bid & 63;
  const int widx = lb * 4 + w;
  const int colbase = lb * 16 + w * 4;

  // ---- stage this wave's 16 weight rows (n = g*4+cc) to LDS, swizzled ----
  {
    const float* Wsrc = (typ == 0) ? Whh0 : ((typ == 1) ? Wih1 : Whh1);
    for (int it = 0; it < 32; ++it) {
      int lin = it * 64 + l;
      int row = lin >> 7, cs = lin & 127, c = cs ^ (row & 7);
      const float* s = Wsrc + (size_t)((row >> 2) * 1024 + colbase + (row & 3)) * 1024 + c * 8;
      f32x4 v0 = *(const f32x4*)s;
      f32x4 v1 = *(const f32x4*)(s + 4);
      bf16x8 o;
      for (int j = 0; j < 4; ++j) { o[j] = (bf16)v0[j]; o[j + 4] = (bf16)v1[j]; }
      *(bf16x8*)&wlds[w][row * 1024 + cs * 8] = o;
    }
  }
  if (tid < 4) tokv[tid] = 0;
  __syncthreads();

  const int gcol = (r16 >> 2) * 1024 + colbase + (r16 & 3);  // lane's gx/bias column
  const int b0s = (r16 >> 2) & 1, b1s = (r16 >> 3) & 1;

  // quarter-poll over a 256-word flag group + LDS-token merge (no barrier)
  auto pollq = [&](unsigned* arr, unsigned tgt) {
    unsigned* q = arr + w * 64 + (l & 15) * 4;
    for (;;) {
      unsigned a0 = __hip_atomic_load(q + 0, __ATOMIC_RELAXED, __HIP_MEMORY_SCOPE_AGENT);
      unsigned a1 = __hip_atomic_load(q + 1, __ATOMIC_RELAXED, __HIP_MEMORY_SCOPE_AGENT);
      unsigned a2 = __hip_atomic_load(q + 2, __ATOMIC_RELAXED, __HIP_MEMORY_SCOPE_AGENT);
      unsigned a3 = __hip_atomic_load(q + 3, __ATOMIC_RELAXED, __HIP_MEMORY_SCOPE_AGENT);
      if (__all(a0 >= tgt && a1 >= tgt && a2 >= tgt && a3 >= tgt)) break;
      __builtin_amdgcn_s_sleep(2);
    }
    volatile unsigned* tk = tokv;
    if (l == 0) tk[w] = tgt;
    while (tk[0] < tgt || tk[1] < tgt || tk[2] < tgt || tk[3] < tgt) {
    }
    asm volatile("" ::: "memory");
  };
  auto poll1 = [&](unsigned* p, unsigned tgt) {
    while (__hip_atomic_load(p, __ATOMIC_RELAXED, __HIP_MEMORY_SCOPE_AGENT) < tgt)
      __builtin_amdgcn_s_sleep(2);
    asm volatile("" ::: "memory");
  };
  // MFMA chain over a 32KB tile plane: lane (r16=n, kq) accumulates C[b][n]
  auto chain = [&](const bf16* plane) -> f32x4 {
    f32x4 acc = (f32x4){0.f, 0.f, 0.f, 0.f};
    const char* hp = (const char*)plane;
#pragma unroll 8
    for (int kk = 0; kk < 32; ++kk) {
      int tl = kk * 8 + kq * 2;
      unsigned long long lo = *(const unsigned long long*)(hp + tl * 128 + r16 * 8);
      unsigned long long hi = *(const unsigned long long*)(hp + tl * 128 + 128 + r16 * 8);
      union { struct { unsigned long long a, b; } u; bf16x8 v; } A;
      A.u.a = lo;
      A.u.b = hi;
      bf16x8 Bf = *(const bf16x8*)&wlds[w][r16 * 1024 + (((kk * 4 + kq) ^ (r16 & 7)) << 3)];
      acc = __builtin_amdgcn_mfma_f32_16x16x32_bf16(A.v, Bf, acc, 0, 0, 0);
    }
    return acc;
  };

  if (typ == 1) {
    // ================= B group: gx1[t] = Wih1 * h0[t] + bsum1 =================
    const float bsv = bsum1[gcol];
    unsigned* const myflag = fB + widx;
    unsigned* const partner = fL1 + widx;
    for (int t = 0; t < T; ++t) {
      if (t >= RING) poll1(partner, (unsigned)(t - RING + 1));  // ring slot free
      pollq(fL0, (unsigned)(t + 1));                            // h0[t] ready
      f32x4 acc = chain(hs0t + (size_t)t * 16384);
      for (int r = 0; r < 4; ++r) acc[r] += bsv;
      float* dst = gx1 + (size_t)(t & (RING - 1)) * 65536 + widx * 256 + r16 * 16 + kq * 4;
      asm volatile("global_store_dwordx4 %0, %1, off sc0 sc1" ::"v"(dst), "v"(acc) : "memory");
      asm volatile("s_waitcnt vmcnt(0)" ::: "memory");
      if (l == 0)
        __hip_atomic_store(myflag, (unsigned)(t + 1), __ATOMIC_RELAXED, __HIP_MEMORY_SCOPE_AGENT);
    }
    return;
  }

  // ================= L0 / L1 recurrence =================
  float cst[4] = {0.f, 0.f, 0.f, 0.f};
  unsigned* const myflag = (typ == 0) ? (fL0 + widx) : (fL1 + widx);
  unsigned* const bpartner = fB + widx;
  bf16* const houts = (typ == 0) ? hs0t : hs1t;

  for (int t = 0; t < T; ++t) {
    float gxv[4];
    if (typ == 0) {  // prefetch gx before the wait
      for (int r = 0; r < 4; ++r)
        gxv[r] = gx[(size_t)(t * 16 + kq * 4 + r) * 4096 + gcol];
    }
    // waits
    if (typ == 0) {
      if (t > 0) pollq(fL0, (unsigned)t);
    } else {
      poll1(bpartner, (unsigned)(t + 1));  // gx1[t] ready
      if (t > 0) pollq(fL1, (unsigned)t);  // h1[t-1] ready
    }
    // matmul
    f32x4 acc = (f32x4){0.f, 0.f, 0.f, 0.f};
    if (t > 0) acc = chain(houts + (size_t)(t - 1) * 16384);
    if (typ == 0) {
      for (int r = 0; r < 4; ++r) acc[r] += gxv[r];
    } else {
      const float* gp = gx1 + (size_t)(t & (RING - 1)) * 65536 + widx * 256 + r16 * 16 + kq * 4;
      f32x4 g1;
      asm volatile("global_load_dwordx4 %0, %1, off sc0 sc1\ns_waitcnt vmcnt(0)"
                   : "=v"(g1) : "v"(gp) : "memory");
      for (int r = 0; r < 4; ++r) acc[r] += g1[r];
    }
    // gate gather (3 shfl rounds over n-dim) + fusion
    float hv[4];
    for (int r = 0; r < 4; ++r) {
      float own = acc[r];
      float p4 = __shfl_xor(own, 4, 64);
      float ev = b0s ? p4 : own;   // gate bit0 = 0  (i or g~)
      float ov = b0s ? own : p4;   // gate bit0 = 1  (f or o)
      float ev8 = __shfl_xor(ev, 8, 64);
      float ov8 = __shfl_xor(ov, 8, 64);
      float xi = b1s ? ev8 : ev;
      float xf = b1s ? ov8 : ov;
      float xg = b1s ? ev : ev8;
      float xo = b1s ? ov : ov8;
      float ig = 1.f / (1.f + __expf(-xi));
      float fg = 1.f / (1.f + __expf(-xf));
      float eg = __expf(2.f * xg);
      float gv = 1.f - 2.f / (eg + 1.f);
      float og = 1.f / (1.f + __expf(-xo));
      cst[r] = fg * cst[r] + ig * gv;
      float ec = __expf(2.f * cst[r]);
      float th = 1.f - 2.f / (ec + 1.f);
      hv[r] = og * th;
    }
    // in-wave transpose via LDS bounce: [col][b] -> [b][4 cols]
    if (r16 < 4) {
      volatile unsigned short* hbp = hb[w];
      for (int r = 0; r < 4; ++r) {
        bf16 hbv = (bf16)hv[r];
        hbp[(kq * 4 + r) * 4 + r16] = __builtin_bit_cast(unsigned short, hbv);
      }
    }
    unsigned long long rowv = 0;
    if (l < 16) rowv = *(volatile unsigned long long*)&hb[w][l * 4];
    if (l < 16) {
      char* dst = (char*)houts + (size_t)t * 32768 + widx * 128 + l * 8;
      asm volatile("global_store_dwordx2 %0, %1, off sc0 sc1" ::"v"(dst), "v"(rowv) : "memory");
    }
    asm volatile("s_waitcnt vmcnt(0)" ::: "memory");
    if (l == 0)
      __hip_atomic_store(myflag, (unsigned)(t + 1), __ATOMIC_RELAXED, __HIP_MEMORY_SCOPE_AGENT);
    // row-major mirror for projection (off critical path, plain cached stores)
    if (typ == 1 + 1 && l < 16) {  // typ == 2
      *(unsigned long long*)((char*)hs1rm + ((size_t)(t * 16 + l) * 1024 + colbase) * 2) = rowv;
    }
  }
}

extern "C" void kernel_launch(void* const* d_in, const int* in_sizes, int n_in,
                              void* d_out, int out_size, void* d_ws, size_t ws_size,
                              hipStream_t stream) {
  const int* x = (const int*)d_in[0];
  const float* emb = (const float*)d_in[1];
  const float* Wih0 = (const float*)d_in[2];
  const float* Whh0 = (const float*)d_in[3];
  const float* bih0 = (const float*)d_in[4];
  const float* bhh0 = (const float*)d_in[5];
  const float* Wih1 = (const float*)d_in[6];
  const float* Whh1 = (const float*)d_in[7];
  const float* bih1 = (const float*)d_in[8];
  const float* bhh1 = (const float*)d_in[9];
  const float* Wout = (const float*)d_in[10];
  const float* bout = (const float*)d_in[11];

  const int T = 512, H = 1024, V = 32000;
  const int M = T * 16;
  const size_t bfb = (size_t)M * H * 2;  // 16 MiB bf16 plane
  const size_t out_bytes = (size_t)out_size * 4;

  // ws: hs1rm (projection input, must survive) + bsums + flags  (~16.1 MB)
  char* p = (char*)d_ws;
  bf16* hs1rm = (bf16*)p;         p += bfb;
  float* bsum0 = (float*)p;       p += 4096 * 4;
  float* bsum1 = (float*)p;       p += 4096 * 4;
  unsigned* flags = (unsigned*)p; p += FLAG_WORDS * 4;

  // d_out scratch (dead until projection writes it):
  float* gx = (float*)d_out;                                   // 134 MB @ head
  float* gx1 = (float*)((char*)d_out + (512ull << 20));        // 2 MB ring
  char* tail = (char*)d_out + out_bytes - 3 * bfb;             // 48 MB tail
  bf16* xe = (bf16*)tail;
  bf16* hs0t = (bf16*)(tail + bfb);
  bf16* hs1t = (bf16*)(tail + 2 * bfb);

  init_misc<<<64, 256, 0, stream>>>(bih0, bhh0, bih1, bhh1, bsum0, bsum1, flags);
  embed_gather<<<M, 256, 0, stream>>>(x, emb, xe, T);
  gemm_bf16<0><<<(M / 128) * (4096 / 128), 256, 0, stream>>>(xe, Wih0, bsum0, gx, M, 4096, H, 0);
  lstm_pipe3<<<192, 256, 0, stream>>>(gx, Whh0, Wih1, Whh1, bsum1, hs0t, hs1t, gx1, hs1rm,
                                      flags, T);
  gemm_bf16<1><<<(M / 128) * (V / 128), 256, 0, stream>>>(hs1rm, Wout, bout, (float*)d_out,
                                                          M, V, H, T);
}